// Round 1
// baseline (7320.621 us; speedup 1.0000x reference)
//
#include <hip/hip_runtime.h>

#define N_PTS 16384
#define M_PTS 4096
#define D_INF 64
#define D_OUTF 128
#define KNN 16
#define DF 67   // 3 + 64

// ---------------- squared norms of p, numpy op order ----------------
__global__ __launch_bounds__(256) void sp_kernel(const float* __restrict__ p,
                                                 float* __restrict__ spn) {
  int j = blockIdx.x * 256 + threadIdx.x;
  float a = p[3 * j], b = p[3 * j + 1], c = p[3 * j + 2];
  spn[j] = __fadd_rn(__fadd_rn(__fmul_rn(a, a), __fmul_rn(b, b)), __fmul_rn(c, c));
}

// ---------------- FPS: single block, points+dists in VGPRs ----------------
#define FPS_T 512
#define FPS_PPT 32  // 512*32 = 16384

__global__ __launch_bounds__(FPS_T) void fps_kernel(const float* __restrict__ p,
                                                    int* __restrict__ sidx,
                                                    float* __restrict__ np_out) {
  const int t = threadIdx.x;
  float px[FPS_PPT], py[FPS_PPT], pz[FPS_PPT], dd[FPS_PPT];
#pragma unroll
  for (int k = 0; k < FPS_PPT; ++k) {
    int j = t + (k << 9);
    px[k] = p[3 * j]; py[k] = p[3 * j + 1]; pz[k] = p[3 * j + 2];
    dd[k] = INFINITY;
  }
  __shared__ float s_wmax[FPS_T / 64];
  __shared__ float s_last[3];
  __shared__ int s_widx;
  if (t == 0) {
    s_widx = 0x7FFFFFFF;
    s_last[0] = px[0]; s_last[1] = py[0]; s_last[2] = pz[0];
    sidx[0] = 0;
    np_out[0] = px[0]; np_out[1] = py[0]; np_out[2] = pz[0];
  }
  __syncthreads();
  for (int i = 1; i < M_PTS; ++i) {
    float lx = s_last[0], ly = s_last[1], lz = s_last[2];
    float tmax = -INFINITY;
#pragma unroll
    for (int k = 0; k < FPS_PPT; ++k) {
      // numpy order: ((dx*dx + dy*dy) + dz*dz), no fma contraction
      float dx = __fsub_rn(px[k], lx);
      float dy = __fsub_rn(py[k], ly);
      float dz = __fsub_rn(pz[k], lz);
      float d = __fadd_rn(__fadd_rn(__fmul_rn(dx, dx), __fmul_rn(dy, dy)),
                          __fmul_rn(dz, dz));
      float nd = fminf(dd[k], d);
      dd[k] = nd;
      tmax = fmaxf(tmax, nd);
    }
    float wmax = tmax;
#pragma unroll
    for (int off = 32; off >= 1; off >>= 1)
      wmax = fmaxf(wmax, __shfl_xor(wmax, off));
    if ((t & 63) == 0) s_wmax[t >> 6] = wmax;
    __syncthreads();  // A
    float gmax = s_wmax[0];
#pragma unroll
    for (int wv = 1; wv < FPS_T / 64; ++wv) gmax = fmaxf(gmax, s_wmax[wv]);
    int m = 0x7FFFFFFF;
    float cx = 0.f, cy = 0.f, cz = 0.f;
    if (tmax == gmax) {
      // smallest owned global index with dd == gmax (first-occurrence argmax)
#pragma unroll
      for (int k = FPS_PPT - 1; k >= 0; --k) {
        if (dd[k] == gmax) { m = t + (k << 9); cx = px[k]; cy = py[k]; cz = pz[k]; }
      }
      atomicMin(&s_widx, m);
    }
    __syncthreads();  // B
    int widx = s_widx;
    if (m != 0x7FFFFFFF && m == widx) {  // unique winner (indices are unique)
      s_last[0] = cx; s_last[1] = cy; s_last[2] = cz;
      s_widx = 0x7FFFFFFF;
      sidx[i] = m;
      np_out[3 * i] = cx; np_out[3 * i + 1] = cy; np_out[3 * i + 2] = cz;
    }
    __syncthreads();  // C
  }
}

// ---------------- kNN + grouping + maxpool features: one wave per query ----
__global__ __launch_bounds__(256) void knn_feat_kernel(const float* __restrict__ p,
                                                       const float* __restrict__ x,
                                                       const float* __restrict__ spn,
                                                       const int* __restrict__ sidx,
                                                       float* __restrict__ feat) {
  __shared__ float cd[4][256];
  __shared__ int ci[4][256];
  __shared__ int cnt[4];
  __shared__ int s_nn[4][KNN];
  const int w = threadIdx.x >> 6;
  const int lane = threadIdx.x & 63;
  const int q = (blockIdx.x << 2) + w;
  const int qi = sidx[q];
  const float qx = p[3 * qi], qy = p[3 * qi + 1], qz = p[3 * qi + 2];
  const float sn = spn[qi];
  if (lane == 0) cnt[w] = 0;
  // Phase A: per-lane min distance over its 256 candidates
  float lmin = INFINITY;
  for (int it = 0; it < N_PTS / 64; ++it) {
    int j = lane + (it << 6);
    float dot = __fmaf_rn(qz, p[3 * j + 2],
                 __fmaf_rn(qy, p[3 * j + 1], __fmul_rn(qx, p[3 * j])));
    float d2 = __fsub_rn(__fadd_rn(sn, spn[j]), __fmul_rn(2.0f, dot));
    lmin = fminf(lmin, d2);
  }
  // tau = 16th smallest of 64 lane minima (valid upper bound on 16th NN dist)
  float mv = lmin;
  float tau = INFINITY;
#pragma unroll
  for (int r = 0; r < KNN; ++r) {
    float rmin = mv;
#pragma unroll
    for (int off = 32; off >= 1; off >>= 1) rmin = fminf(rmin, __shfl_xor(rmin, off));
    tau = rmin;
    unsigned long long msk = __ballot(mv == rmin);
    if (lane == (int)(__ffsll(msk) - 1)) mv = INFINITY;
  }
  __syncthreads();
  // Phase B: compact all candidates with d2 <= tau (expected ~18-40)
  for (int it = 0; it < N_PTS / 64; ++it) {
    int j = lane + (it << 6);
    float dot = __fmaf_rn(qz, p[3 * j + 2],
                 __fmaf_rn(qy, p[3 * j + 1], __fmul_rn(qx, p[3 * j])));
    float d2 = __fsub_rn(__fadd_rn(sn, spn[j]), __fmul_rn(2.0f, dot));
    if (d2 <= tau) {
      int pos = atomicAdd(&cnt[w], 1);
      if (pos < 256) { cd[w][pos] = d2; ci[w][pos] = j; }
    }
  }
  __syncthreads();
  // Phase C: extract 16 smallest by (value, index) — stable top_k semantics
  int C = min(cnt[w], 256);
  float vv[4]; int ii[4];
#pragma unroll
  for (int s = 0; s < 4; ++s) {
    int pos = lane + (s << 6);
    bool ok = pos < C;
    vv[s] = ok ? cd[w][pos] : INFINITY;
    ii[s] = ok ? ci[w][pos] : 0x7FFFFFFF;
  }
#pragma unroll
  for (int r = 0; r < KNN; ++r) {
    float bv = vv[0]; int bi = ii[0]; int bs = 0;
#pragma unroll
    for (int s = 1; s < 4; ++s) {
      bool tk = (vv[s] < bv) || (vv[s] == bv && ii[s] < bi);
      bv = tk ? vv[s] : bv; bi = tk ? ii[s] : bi; bs = tk ? s : bs;
    }
    float rv = bv; int ri = bi;
#pragma unroll
    for (int off = 32; off >= 1; off >>= 1) {
      float ov = __shfl_xor(rv, off); int oi = __shfl_xor(ri, off);
      bool tk = (ov < rv) || (ov == rv && oi < ri);
      rv = tk ? ov : rv; ri = tk ? oi : ri;
    }
    if (bi == ri) {  // my local-best slot won: retire it
#pragma unroll
      for (int s = 0; s < 4; ++s) if (s == bs) vv[s] = INFINITY;
    }
    if (lane == 0) s_nn[w][r] = ri;
  }
  __syncthreads();
  // Phase D: relative coords, norm scaling, maxpool
  float ax = -INFINITY, ay = -INFINITY, az = -INFINITY, nr = -INFINITY;
  if (lane < KNN) {
    int jn = s_nn[w][lane];
    ax = __fsub_rn(p[3 * jn], qx);
    ay = __fsub_rn(p[3 * jn + 1], qy);
    az = __fsub_rn(p[3 * jn + 2], qz);
    nr = sqrtf(__fadd_rn(__fadd_rn(__fmul_rn(ax, ax), __fmul_rn(ay, ay)),
                         __fmul_rn(az, az)));
  }
  float mnr = nr, mx = ax, my = ay, mz = az;
#pragma unroll
  for (int off = 32; off >= 1; off >>= 1) {
    mnr = fmaxf(mnr, __shfl_xor(mnr, off));
    mx = fmaxf(mx, __shfl_xor(mx, off));
    my = fmaxf(my, __shfl_xor(my, off));
    mz = fmaxf(mz, __shfl_xor(mz, off));
  }
  if (lane == 0) {
    // max over k commutes exactly with the (monotone) division
    float sden = __fadd_rn(mnr, 1e-8f);
    feat[q * DF + 0] = mx / sden;
    feat[q * DF + 1] = my / sden;
    feat[q * DF + 2] = mz / sden;
  }
  float fm = -INFINITY;
#pragma unroll
  for (int k = 0; k < KNN; ++k) {
    int jn = s_nn[w][k];
    fm = fmaxf(fm, x[(jn << 6) + lane]);
  }
  feat[q * DF + 3 + lane] = fm;
}

// ---------------- MLP: h = feat @ W + b ----------------
__global__ __launch_bounds__(128) void mlp_kernel(const float* __restrict__ feat,
                                                  const float* __restrict__ W,
                                                  const float* __restrict__ b,
                                                  float* __restrict__ h) {
  int mrow = blockIdx.x;
  int o = threadIdx.x;
  const float* fr = feat + mrow * DF;
  float acc = b[o];
#pragma unroll
  for (int k = 0; k < DF; ++k) acc = __fmaf_rn(fr[k], W[k * D_OUTF + o], acc);
  h[mrow * D_OUTF + o] = acc;
}

// ---------------- BN column stats (training mode) ----------------
__global__ __launch_bounds__(256) void stats_kernel(const float* __restrict__ h,
                                                    const float* __restrict__ gamma,
                                                    const float* __restrict__ beta,
                                                    float* __restrict__ scsh) {
  int o = blockIdx.x;
  int t = threadIdx.x;
  float s = 0.f, s2 = 0.f;
  for (int mrow = t; mrow < M_PTS; mrow += 256) {
    float v = h[mrow * D_OUTF + o];
    s += v;
    s2 = __fmaf_rn(v, v, s2);
  }
#pragma unroll
  for (int off = 32; off >= 1; off >>= 1) {
    s += __shfl_xor(s, off);
    s2 += __shfl_xor(s2, off);
  }
  __shared__ float as1[4], as2[4];
  if ((t & 63) == 0) { as1[t >> 6] = s; as2[t >> 6] = s2; }
  __syncthreads();
  if (t == 0) {
    float ts = ((as1[0] + as1[1]) + as1[2]) + as1[3];
    float ts2 = ((as2[0] + as2[1]) + as2[2]) + as2[3];
    float mean = ts / (float)M_PTS;
    float var = ts2 / (float)M_PTS - mean * mean;
    var = fmaxf(var, 0.f);
    float sc = gamma[o] / sqrtf(var + 1e-5f);
    scsh[o] = sc;
    scsh[D_OUTF + o] = beta[o] - mean * sc;
  }
}

// ---------------- BN apply + ReLU + n_o ----------------
__global__ __launch_bounds__(256) void bn_kernel(const float* __restrict__ h,
                                                 const float* __restrict__ scsh,
                                                 float* __restrict__ out) {
  int idx = blockIdx.x * 256 + threadIdx.x;
  int o = idx & (D_OUTF - 1);
  float v = __fmaf_rn(h[idx], scsh[o], scsh[D_OUTF + o]);
  out[M_PTS * 3 + idx] = fmaxf(v, 0.f);
  if (idx == 0) out[M_PTS * 3 + M_PTS * D_OUTF] = 4096.0f;  // n_o
}

extern "C" void kernel_launch(void* const* d_in, const int* in_sizes, int n_in,
                              void* d_out, int out_size, void* d_ws, size_t ws_size,
                              hipStream_t stream) {
  const float* p     = (const float*)d_in[0];
  const float* x     = (const float*)d_in[1];
  // d_in[2] = o (offsets) — unused, single cloud
  const float* W     = (const float*)d_in[3];
  const float* b     = (const float*)d_in[4];
  const float* gamma = (const float*)d_in[5];
  const float* beta  = (const float*)d_in[6];
  float* out = (float*)d_out;

  float* wsf  = (float*)d_ws;
  int*   sidx = (int*)d_ws;                    // [4096]
  float* spn  = wsf + 4096;                    // [16384]
  float* feat = spn + N_PTS;                   // [4096 * 67]
  float* h    = feat + M_PTS * DF;             // [4096 * 128]
  float* scsh = h + M_PTS * D_OUTF;            // [256]

  sp_kernel<<<N_PTS / 256, 256, 0, stream>>>(p, spn);
  fps_kernel<<<1, FPS_T, 0, stream>>>(p, sidx, out);
  knn_feat_kernel<<<M_PTS / 4, 256, 0, stream>>>(p, x, spn, sidx, feat);
  mlp_kernel<<<M_PTS, D_OUTF, 0, stream>>>(feat, W, b, h);
  stats_kernel<<<D_OUTF, 256, 0, stream>>>(h, gamma, beta, scsh);
  bn_kernel<<<(M_PTS * D_OUTF) / 256, 256, 0, stream>>>(h, scsh, out);
}